// Round 9
// baseline (178.083 us; speedup 1.0000x reference)
//
#include <hip/hip_runtime.h>

#define NB   8192
#define HW   4096   // 64*64

typedef float vfloat4 __attribute__((ext_vector_type(4)));  // native vec for nt-load

// One 64-lane wave handles TWO samples (grid-stride s=0,1; grid = NB/8 blocks
// of 4 waves). Loads are NONTEMPORAL with a depth-4 register ring prefetch
// (R7 showed plain register staging collapses to a dependent chain; R6/R8
// showed depth 4 == depth 8). Accumulates per sample
//   s0 = sum x, sj = sum j*x, sk = sum k*x, sq = sum (j^2+k^2)*x
// plus first-max argmax (strict '>', increasing per-lane scan order).
// Wave shuffle reduce; lane 0 writes closed-form per-sample loss
//   loss = (mx^2+my^2)*s0 - 2*mx*sj - 2*my*sk + sq
// to ws[b]. Tiny second kernel reduces the 8192 partials (fixed order).
__global__ __launch_bounds__(256) void per_sample_loss(const float* __restrict__ x,
                                                       float* __restrict__ ws) {
    const int t     = threadIdx.x;
    const int lane  = t & 63;
    const int wave  = t >> 6;
    const int gwave = blockIdx.x * 4 + wave;   // 0..2047

    // Per-lane k constants (independent of sample / iteration).
    float kf[4], kk[4];
#pragma unroll
    for (int c = 0; c < 4; ++c) {
        kf[c] = (float)(4 * (lane & 15) + c);
        kk[c] = kf[c] * kf[c];
    }

    for (int s = 0; s < 2; ++s) {
        const int b = s * (NB / 2) + gwave;
        const vfloat4* xp = (const vfloat4*)(x + (size_t)b * HW) + lane;

        // Depth-4 nontemporal prefetch ring.
        vfloat4 r[4];
#pragma unroll
        for (int p = 0; p < 4; ++p)
            r[p] = __builtin_nontemporal_load(xp + p * 64);

        float jf = (float)(lane >> 4);
        int   eb = 4 * lane;          // flat index of component 0 at iter 0

        float s0 = 0.f, sj = 0.f, sk = 0.f, sq = 0.f;
        float maxv = -__builtin_inff();
        int   maxi = 0;

#pragma unroll
        for (int it = 0; it < 16; ++it) {
            const vfloat4 v4 = r[it & 3];
            if (it + 4 < 16)
                r[it & 3] = __builtin_nontemporal_load(xp + (it + 4) * 64);
            const float jj = jf * jf;
#pragma unroll
            for (int c = 0; c < 4; ++c) {
                const float v = v4[c];
                s0 += v;
                sj = fmaf(jf, v, sj);
                sk = fmaf(kf[c], v, sk);
                sq = fmaf(jj + kk[c], v, sq);
                const bool gt = v > maxv;  // strict '>' => first max per lane
                maxv = gt ? v : maxv;
                maxi = gt ? eb + c : maxi;
            }
            jf += 4.0f;
            eb += 256;
        }

        // Wave reduce (64 lanes); ties -> smaller flat index (first max).
#pragma unroll
        for (int off = 32; off > 0; off >>= 1) {
            s0 += __shfl_down(s0, off);
            sj += __shfl_down(sj, off);
            sk += __shfl_down(sk, off);
            sq += __shfl_down(sq, off);
            const float ov = __shfl_down(maxv, off);
            const int   oi = __shfl_down(maxi, off);
            const bool take = (ov > maxv) || (ov == maxv && oi < maxi);
            maxv = take ? ov : maxv;
            maxi = take ? oi : maxi;
        }

        if (lane == 0) {
            const float mx = (float)(maxi >> 6);
            const float my = (float)(maxi & 63);
            ws[b] = (mx * mx + my * my) * s0 - 2.f * mx * sj - 2.f * my * sk + sq;
        }
    }
}

__global__ __launch_bounds__(256) void final_reduce(const float* __restrict__ ws,
                                                    float* __restrict__ out) {
    const int t = threadIdx.x;
    float s = 0.f;
#pragma unroll
    for (int i = 0; i < NB / 256; ++i) s += ws[i * 256 + t];
#pragma unroll
    for (int off = 32; off > 0; off >>= 1) s += __shfl_down(s, off);
    __shared__ float l[4];
    if ((t & 63) == 0) l[t >> 6] = s;
    __syncthreads();
    if (t == 0) out[0] = l[0] + l[1] + l[2] + l[3];
}

extern "C" void kernel_launch(void* const* d_in, const int* in_sizes, int n_in,
                              void* d_out, int out_size, void* d_ws, size_t ws_size,
                              hipStream_t stream) {
    const float* x = (const float*)d_in[0];
    float* out = (float*)d_out;
    float* ws  = (float*)d_ws;   // 8192 floats = 32 KiB scratch

    per_sample_loss<<<NB / 8, 256, 0, stream>>>(x, ws);
    final_reduce<<<1, 256, 0, stream>>>(ws, out);
}